// Round 9
// baseline (2522.088 us; speedup 1.0000x reference)
//
#include <hip/hip_runtime.h>
#include <math.h>

// Batched exact Hungarian (Jonker-Volgenant). One wave per batch; lane l owns
// contiguous columns j = 4l..4l+3 (jj = 4l+k+1): lowest-jj tie-break ==
// prefer-left local tree then lowest-lane ballot == jnp.argmin first-occur.
//
// Round-9 (issue-count surgery; dur tracks VALU issue count, r5/r6/r8):
//  - DEFERRED u/v: in-run scans only read row-start u/v (proved: cur uses
//    the newest tree row's u before its first bump; v[used]/minv[used] are
//    decision-dead). Per-iter update = minv[k]-=delta x4 + u_i+=delta.
//    Row end: u_new=(ui-u_i)@mark+u_i_end, v_new=(v+u_i)@mark-u_i_end
//    (lump-sum rounding ~1ulp, same risk class as fast-sqrt -- validated r8).
//  - vm[] = v (or -inf when used): kills +usedf and m[] mask; argmin reads
//    minv directly (used columns pinned to +inf at mark; exact transform).
//  - fma-contracted ss (explicit fmaf; <=1ulp class) + raw v_sqrt_f32 (r8).
//  - branchy wave-uniform mark at iteration HEAD (r5 position).
//  - unchanged: codes+tree argmin, min3 DPP reduce, ballot+ffs owner,
//    speculative per-lane u/pred prefetch + readlane pulls, way[] in regs.
//
// Output dtype: harness reads d_out as float32; col4row stored as floats.

#define NB   32
#define NN   256
#define ND   4
#define NPT  4
#define INFV 1e9f

#if __has_builtin(__builtin_amdgcn_sqrtf)
__device__ __forceinline__ float fast_sqrtf(float x) { return __builtin_amdgcn_sqrtf(x); }
#else
__device__ __forceinline__ float fast_sqrtf(float x) {
    float r; asm volatile("v_sqrt_f32 %0, %1" : "=v"(r) : "v"(x)); return r;
}
#endif

__device__ __forceinline__ float wave_min_bcast(float x) {
    // 64-lane min in 5 dependent steps (min3 ladder); fill=1e9 never wins.
    const int fill = __float_as_int(INFV);
    int a, c;
    a = __builtin_amdgcn_update_dpp(fill, __float_as_int(x), 0x111, 0xF, 0xF, false); // row_shr:1
    c = __builtin_amdgcn_update_dpp(fill, __float_as_int(x), 0x112, 0xF, 0xF, false); // row_shr:2
    x = fminf(x, fminf(__int_as_float(a), __int_as_float(c)));      // cover 3
    a = __builtin_amdgcn_update_dpp(fill, __float_as_int(x), 0x113, 0xF, 0xF, false); // row_shr:3
    c = __builtin_amdgcn_update_dpp(fill, __float_as_int(x), 0x116, 0xF, 0xF, false); // row_shr:6
    x = fminf(x, fminf(__int_as_float(a), __int_as_float(c)));      // cover 9
    a = __builtin_amdgcn_update_dpp(fill, __float_as_int(x), 0x117, 0xF, 0xF, false); // row_shr:7
    x = fminf(x, __int_as_float(a));                                // cover 16
    a = __builtin_amdgcn_update_dpp(fill, __float_as_int(x), 0x142, 0xF, 0xF, false); // row_bcast:15
    x = fminf(x, __int_as_float(a));
    a = __builtin_amdgcn_update_dpp(fill, __float_as_int(x), 0x143, 0xF, 0xF, false); // row_bcast:31
    x = fminf(x, __int_as_float(a));                                // lane63 = global
    return __int_as_float(__builtin_amdgcn_readlane(__float_as_int(x), 63));
}

__device__ __forceinline__ float readlane_f(float v, int lane) {
    return __int_as_float(__builtin_amdgcn_readlane(__float_as_int(v), lane));
}

__global__ __launch_bounds__(64) void hungarian_kernel(
    const float* __restrict__ pred, const float* __restrict__ gt,
    float* __restrict__ out)
{
#pragma clang fp contract(off)
    const int b    = blockIdx.x;
    const int lane = threadIdx.x;

    __shared__ float s_pred[NN][ND];   // pred points, 16B rows
    __shared__ float s_u[NN + 1];      // row potentials (1-based), row-start values
    __shared__ int   s_p[NN + 1];      // p[jj] = matched row (1-based)
    __shared__ int   s_way[NN];        // way, swizzled: [k*64 + lane]

    const float* pb = pred + (size_t)b * NN * ND;
    const float* gb = gt   + (size_t)b * NN * ND;

    #pragma unroll
    for (int k = 0; k < NPT; ++k) {
        int idx = lane + 64 * k;
        float4 pv = ((const float4*)pb)[idx];
        *(float4*)&s_pred[idx][0] = pv;
    }
    float gx[NPT], gy[NPT], gz[NPT], gw[NPT];
    #pragma unroll
    for (int k = 0; k < NPT; ++k) {
        float4 gv = ((const float4*)gb)[4 * lane + k];
        gx[k] = gv.x; gy[k] = gv.y; gz[k] = gv.z; gw[k] = gv.w;
    }
    #pragma unroll
    for (int k = 0; k < NPT; ++k) {
        int jj = lane + 64 * k;
        s_u[jj] = 0.f; s_p[jj] = 0;
    }
    if (lane == 0) { s_u[NN] = 0.f; s_p[NN] = 0; }
    float v[NPT]; int pl[NPT];
    #pragma unroll
    for (int k = 0; k < NPT; ++k) { v[k] = 0.f; pl[k] = 0; }
    const float FINF = __int_as_float(0x7f800000);   // +inf
    const float NINF = __int_as_float(0xff800000);   // -inf
    __syncthreads();

    for (int i = 1; i <= NN; ++i) {
        if (lane == 0) s_p[0] = i;
        int codes[NPT];                    // (jj | pl<<12), constant per row
        #pragma unroll
        for (int k = 0; k < NPT; ++k) codes[k] = (4 * lane + k + 1) | (pl[k] << 12);
        float minv[NPT], vm[NPT], base_u[NPT], base_v[NPT];
        int   wayr[NPT];
        #pragma unroll
        for (int k = 0; k < NPT; ++k) {
            minv[k] = INFV; vm[k] = v[k]; base_u[k] = 0.f; base_v[k] = 0.f; wayr[k] = 0;
        }
        float u_i = 0.f;                          // sequential sum of deltas == ref u[i]
        int   j1  = 0;
        float ui  = 0.f;                          // u[i]=0 at row start
        float4 pr = *(const float4*)&s_pred[i - 1][0];
        int   i0n = i;

        for (int it = 0; it < NN + 2; ++it) {
            // mark column j1 used (kk/owner wave-uniform -> scalar 4-way branch)
            if (j1 > 0) {
                int jm1 = j1 - 1;
                int kk  = jm1 & 3;
                bool own = (jm1 >> 2) == lane;
                float bu = ui - u_i;              // u_new = bu + u_i_end
                if (kk == 0) {
                    vm[0]     = own ? NINF : vm[0];
                    minv[0]   = own ? FINF : minv[0];
                    base_u[0] = own ? bu   : base_u[0];
                    base_v[0] = own ? (v[0] + u_i) : base_v[0];
                } else if (kk == 1) {
                    vm[1]     = own ? NINF : vm[1];
                    minv[1]   = own ? FINF : minv[1];
                    base_u[1] = own ? bu   : base_u[1];
                    base_v[1] = own ? (v[1] + u_i) : base_v[1];
                } else if (kk == 2) {
                    vm[2]     = own ? NINF : vm[2];
                    minv[2]   = own ? FINF : minv[2];
                    base_u[2] = own ? bu   : base_u[2];
                    base_v[2] = own ? (v[2] + u_i) : base_v[2];
                } else {
                    vm[3]     = own ? NINF : vm[3];
                    minv[3]   = own ? FINF : minv[3];
                    base_u[3] = own ? bu   : base_u[3];
                    base_v[3] = own ? (v[3] + u_i) : base_v[3];
                }
            }
            // scan owned columns; fma-contracted ss + fast sqrt (decisions only)
            #pragma unroll
            for (int k = 0; k < NPT; ++k) {
                float dx = pr.x - gx[k], dy = pr.y - gy[k];
                float dz = pr.z - gz[k], dw = pr.w - gw[k];
                float ss = dx * dx;
                ss = __builtin_fmaf(dy, dy, ss);
                ss = __builtin_fmaf(dz, dz, ss);
                ss = __builtin_fmaf(dw, dw, ss);
                float cur = (fast_sqrtf(ss) - ui) - vm[k];   // used: -(-inf) = +inf
                bool upd = cur < minv[k];
                wayr[k] = upd ? j1 : wayr[k];
                minv[k] = fminf(minv[k], cur);
            }
            // 2-level tree argmin on minv (strict <, prefer-left = first-occur)
            bool s01 = minv[1] < minv[0];
            float v01 = s01 ? minv[1] : minv[0];
            int   c01 = s01 ? codes[1] : codes[0];
            bool s23 = minv[3] < minv[2];
            float v23 = s23 ? minv[3] : minv[2];
            int   c23 = s23 ? codes[3] : codes[2];
            bool sF  = v23 < v01;
            float best       = sF ? v23 : v01;
            int   code_local = sF ? c23 : c01;
            // speculative prefetch of candidate row's u/pred
            int psel = code_local >> 12;
            int pidx = (psel > 0) ? (psel - 1) : 0;
            float  u_spec = s_u[psel];
            float4 p_spec = *(const float4*)&s_pred[pidx][0];
            // wave argmin: value min via DPP; owner = lowest lane at min
            const float gmin = wave_min_bcast(best);
            unsigned long long msk = __ballot(best == gmin);
            int owner = __ffsll(msk) - 1;
            int code  = __builtin_amdgcn_readlane(code_local, owner);
            int j1n   = code & 0xFFF;
            i0n       = code >> 12;
            // minimal updates: minv -= delta (used stay +inf); u_i += delta
            const float delta = gmin;
            #pragma unroll
            for (int k = 0; k < NPT; ++k) minv[k] -= delta;
            u_i += delta;
            j1 = j1n;
            if (i0n == 0) break;                  // free column (updates done)
            ui   = readlane_f(u_spec, owner);
            pr.x = readlane_f(p_spec.x, owner);
            pr.y = readlane_f(p_spec.y, owner);
            pr.z = readlane_f(p_spec.z, owner);
            pr.w = readlane_f(p_spec.w, owner);
        }

        // flush way registers to LDS (stride-1 per k, conflict-free)
        #pragma unroll
        for (int k = 0; k < NPT; ++k) s_way[(k << 6) + lane] = wayr[k];
        __syncthreads();   // way/p0 writes visible before augment reads
        // deferred write-back: used columns identified by minv==+inf
        #pragma unroll
        for (int k = 0; k < NPT; ++k) {
            bool used = (minv[k] == FINF);
            if (used) s_u[pl[k]] = base_u[k] + u_i;     // exec-masked ds_write
            v[k] = used ? (base_v[k] - u_i) : v[k];
        }
        if (lane == 0) s_u[i] = u_i;
        // augment along way chain (uniform walk; owners update pl)
        int j = j1;
        while (j != 0) {
            int jm1 = j - 1;
            int jp  = s_way[((jm1 & 3) << 6) + (jm1 >> 2)];
            int val = s_p[jp];
            if (lane == 0) s_p[j] = val;
            bool own = (jm1 >> 2) == lane;
            int  kk  = jm1 & 3;
            #pragma unroll
            for (int k = 0; k < NPT; ++k)
                pl[k] = (own && kk == k) ? val : pl[k];
            j = jp;
        }
        __syncthreads();   // u/p writes visible before next row's spec reads
    }

    // outputs (float32): col4row[b][r-1] = j ; total_cost[b]
    // IEEE sqrtf here (threshold on cost is loose; col4row must be exact).
    float tot = 0.f;
    #pragma unroll
    for (int k = 0; k < NPT; ++k) {
        int j = 4 * lane + k;
        int r = pl[k];                        // 1-based matched row
        out[b * NN + (r - 1)] = (float)j;
        float4 p4 = *(const float4*)&s_pred[r - 1][0];
        float dx = p4.x - gx[k], dy = p4.y - gy[k];
        float dz = p4.z - gz[k], dw = p4.w - gw[k];
        tot += sqrtf(dx * dx + dy * dy + dz * dz + dw * dw);
    }
    for (int off = 32; off; off >>= 1) tot += __shfl_xor(tot, off);
    if (lane == 0) out[NB * NN + b] = tot;
}

extern "C" void kernel_launch(void* const* d_in, const int* in_sizes, int n_in,
                              void* d_out, int out_size, void* d_ws, size_t ws_size,
                              hipStream_t stream) {
    const float* pred = (const float*)d_in[0];
    const float* gt   = (const float*)d_in[1];
    float* out = (float*)d_out;
    hipLaunchKernelGGL(hungarian_kernel, dim3(NB), dim3(64), 0, stream,
                       pred, gt, out);
}

// Round 10
// 2138.228 us; speedup vs baseline: 1.1795x; 1.1795x over previous
//
#include <hip/hip_runtime.h>
#include <math.h>

// Batched exact Hungarian (Jonker-Volgenant). One wave per batch; lane l owns
// contiguous columns j = 4l..4l+3 (jj = 4l+k+1): lowest-jj tie-break ==
// prefer-left local tree then lowest-lane ballot == jnp.argmin first-occur.
//
// Round-10 = r8 branchless structure + r9 arithmetic (both HW-validated):
//  - NO branches in the iteration body (r7/r9 lesson: uniform branch chains
//    cost ~130cy/iter). Mark is guard-free cndmask: jm1=-1 matches no lane.
//  - deferred u/v (r9, absmax-0-validated): scan reads row-start u/v only;
//    per-iter update is just minv[k]-=delta + u_i+=delta (scalar). Row end
//    reconstructs: u_new = ucol + u_i_end (ucol = ui-u_i at mark),
//    v_new = (v - u_i_end) + mcol (mcol = u_i at mark).
//  - vm[k] = v[k] or -inf when used: cur=+inf for used (freezes wayr),
//    minv[k]=+inf masks argmin directly (no +usedf mask adds).
//  - fma-contracted ss + raw v_sqrt_f32 (r8/r9-validated, decisions only).
//  - codes+tree argmin, min3 DPP reduce, ballot+ffs owner, speculative
//    per-lane u/pred prefetch + readlane pulls, way[] in regs (r8).
//
// Output dtype: harness reads d_out as float32; col4row stored as floats.

#define NB   32
#define NN   256
#define ND   4
#define NPT  4
#define INFV 1e9f

#if __has_builtin(__builtin_amdgcn_sqrtf)
__device__ __forceinline__ float fast_sqrtf(float x) { return __builtin_amdgcn_sqrtf(x); }
#else
__device__ __forceinline__ float fast_sqrtf(float x) {
    float r; asm volatile("v_sqrt_f32 %0, %1" : "=v"(r) : "v"(x)); return r;
}
#endif

__device__ __forceinline__ float wave_min_bcast(float x) {
    // 64-lane min in 5 dependent steps (min3 ladder); fill=1e9 never wins.
    const int fill = __float_as_int(INFV);
    int a, c;
    a = __builtin_amdgcn_update_dpp(fill, __float_as_int(x), 0x111, 0xF, 0xF, false); // row_shr:1
    c = __builtin_amdgcn_update_dpp(fill, __float_as_int(x), 0x112, 0xF, 0xF, false); // row_shr:2
    x = fminf(x, fminf(__int_as_float(a), __int_as_float(c)));      // cover 3
    a = __builtin_amdgcn_update_dpp(fill, __float_as_int(x), 0x113, 0xF, 0xF, false); // row_shr:3
    c = __builtin_amdgcn_update_dpp(fill, __float_as_int(x), 0x116, 0xF, 0xF, false); // row_shr:6
    x = fminf(x, fminf(__int_as_float(a), __int_as_float(c)));      // cover 9
    a = __builtin_amdgcn_update_dpp(fill, __float_as_int(x), 0x117, 0xF, 0xF, false); // row_shr:7
    x = fminf(x, __int_as_float(a));                                // cover 16
    a = __builtin_amdgcn_update_dpp(fill, __float_as_int(x), 0x142, 0xF, 0xF, false); // row_bcast:15
    x = fminf(x, __int_as_float(a));
    a = __builtin_amdgcn_update_dpp(fill, __float_as_int(x), 0x143, 0xF, 0xF, false); // row_bcast:31
    x = fminf(x, __int_as_float(a));                                // lane63 = global
    return __int_as_float(__builtin_amdgcn_readlane(__float_as_int(x), 63));
}

__device__ __forceinline__ float readlane_f(float v, int lane) {
    return __int_as_float(__builtin_amdgcn_readlane(__float_as_int(v), lane));
}

__global__ __launch_bounds__(64) void hungarian_kernel(
    const float* __restrict__ pred, const float* __restrict__ gt,
    float* __restrict__ out)
{
#pragma clang fp contract(off)
    const int b    = blockIdx.x;
    const int lane = threadIdx.x;

    __shared__ float s_pred[NN][ND];   // pred points, 16B rows
    __shared__ float s_u[NN + 1];      // row potentials (1-based), row-start values
    __shared__ int   s_p[NN + 1];      // p[jj] = matched row (1-based)
    __shared__ int   s_way[NN];        // way, swizzled: [k*64 + lane]

    const float* pb = pred + (size_t)b * NN * ND;
    const float* gb = gt   + (size_t)b * NN * ND;

    #pragma unroll
    for (int k = 0; k < NPT; ++k) {
        int idx = lane + 64 * k;
        float4 pv = ((const float4*)pb)[idx];
        *(float4*)&s_pred[idx][0] = pv;
    }
    float gx[NPT], gy[NPT], gz[NPT], gw[NPT];
    #pragma unroll
    for (int k = 0; k < NPT; ++k) {
        float4 gv = ((const float4*)gb)[4 * lane + k];
        gx[k] = gv.x; gy[k] = gv.y; gz[k] = gv.z; gw[k] = gv.w;
    }
    #pragma unroll
    for (int k = 0; k < NPT; ++k) {
        int jj = lane + 64 * k;
        s_u[jj] = 0.f; s_p[jj] = 0;
    }
    if (lane == 0) { s_u[NN] = 0.f; s_p[NN] = 0; }
    float v[NPT]; int pl[NPT];
    #pragma unroll
    for (int k = 0; k < NPT; ++k) { v[k] = 0.f; pl[k] = 0; }
    const float FINF = __int_as_float(0x7f800000);   // +inf
    const float NINF = __int_as_float(0xff800000);   // -inf
    __syncthreads();

    for (int i = 1; i <= NN; ++i) {
        if (lane == 0) s_p[0] = i;
        int codes[NPT];                    // (jj | pl<<12), constant per row
        #pragma unroll
        for (int k = 0; k < NPT; ++k) codes[k] = (4 * lane + k + 1) | (pl[k] << 12);
        float minv[NPT], vm[NPT], ucol[NPT], mcol[NPT];
        int   wayr[NPT];
        #pragma unroll
        for (int k = 0; k < NPT; ++k) {
            minv[k] = INFV; vm[k] = v[k]; ucol[k] = 0.f; mcol[k] = 0.f; wayr[k] = 0;
        }
        float u_i = 0.f;                          // running sum of deltas == ref u[i]
        int   j1  = 0;
        float ui  = 0.f;                          // u[p[j1]] row-start value
        float4 pr = *(const float4*)&s_pred[i - 1][0];
        int   i0n = i;

        for (int it = 0; it < NN + 2; ++it) {
            // branchless mark: jm1=-1 on first iter matches no lane
            const int   jm1 = j1 - 1;             // wave-uniform
            const float bu  = ui - u_i;           // SGPR arithmetic
            #pragma unroll
            for (int k = 0; k < NPT; ++k) {
                bool hit = (4 * lane + k) == jm1;
                vm[k]   = hit ? NINF : vm[k];     // freezes wayr; cur=+inf
                minv[k] = hit ? FINF : minv[k];   // masks argmin
                ucol[k] = hit ? bu   : ucol[k];   // u_new = ucol + u_i_end
                mcol[k] = hit ? u_i  : mcol[k];   // v_new = (v - u_i_end) + mcol
            }
            // scan owned columns; fma ss + fast sqrt (decisions only)
            #pragma unroll
            for (int k = 0; k < NPT; ++k) {
                float dx = pr.x - gx[k], dy = pr.y - gy[k];
                float dz = pr.z - gz[k], dw = pr.w - gw[k];
                float ss = dx * dx;
                ss = __builtin_fmaf(dy, dy, ss);
                ss = __builtin_fmaf(dz, dz, ss);
                ss = __builtin_fmaf(dw, dw, ss);
                float cur = (fast_sqrtf(ss) - ui) - vm[k];   // used: +inf
                bool upd = cur < minv[k];
                wayr[k] = upd ? j1 : wayr[k];
                minv[k] = fminf(minv[k], cur);
            }
            // 2-level tree argmin on minv (strict <, prefer-left = first-occur)
            bool s01 = minv[1] < minv[0];
            float v01 = s01 ? minv[1] : minv[0];
            int   c01 = s01 ? codes[1] : codes[0];
            bool s23 = minv[3] < minv[2];
            float v23 = s23 ? minv[3] : minv[2];
            int   c23 = s23 ? codes[3] : codes[2];
            bool sF  = v23 < v01;
            float best       = sF ? v23 : v01;
            int   code_local = sF ? c23 : c01;
            // speculative prefetch of candidate row's u/pred
            int psel = code_local >> 12;
            int pidx = (psel > 0) ? (psel - 1) : 0;
            float  u_spec = s_u[psel];
            float4 p_spec = *(const float4*)&s_pred[pidx][0];
            // wave argmin: value min via DPP; owner = lowest lane at min
            const float gmin = wave_min_bcast(best);
            unsigned long long msk = __ballot(best == gmin);
            int owner = __ffsll(msk) - 1;
            int code  = __builtin_amdgcn_readlane(code_local, owner);
            int j1n   = code & 0xFFF;
            i0n       = code >> 12;
            // minimal updates: minv -= delta (used stay +inf); u_i += delta
            const float delta = gmin;
            #pragma unroll
            for (int k = 0; k < NPT; ++k) minv[k] -= delta;
            u_i += delta;
            j1 = j1n;
            if (i0n == 0) break;                  // free column (updates done)
            ui   = readlane_f(u_spec, owner);
            pr.x = readlane_f(p_spec.x, owner);
            pr.y = readlane_f(p_spec.y, owner);
            pr.z = readlane_f(p_spec.z, owner);
            pr.w = readlane_f(p_spec.w, owner);
        }

        // flush way registers to LDS (stride-1 per k, conflict-free)
        #pragma unroll
        for (int k = 0; k < NPT; ++k) s_way[(k << 6) + lane] = wayr[k];
        __syncthreads();   // way/p0 writes visible before augment reads
        // deferred write-back: used columns identified by minv==+inf
        #pragma unroll
        for (int k = 0; k < NPT; ++k) {
            bool used = (minv[k] == FINF);
            if (used) s_u[pl[k]] = ucol[k] + u_i;        // exec-masked ds_write
            v[k] = used ? ((v[k] - u_i) + mcol[k]) : v[k];
        }
        if (lane == 0) s_u[i] = u_i;
        // augment along way chain (uniform walk; owners update pl)
        int j = j1;
        while (j != 0) {
            int jm1 = j - 1;
            int jp  = s_way[((jm1 & 3) << 6) + (jm1 >> 2)];
            int val = s_p[jp];
            if (lane == 0) s_p[j] = val;
            bool own = (jm1 >> 2) == lane;
            int  kk  = jm1 & 3;
            #pragma unroll
            for (int k = 0; k < NPT; ++k)
                pl[k] = (own && kk == k) ? val : pl[k];
            j = jp;
        }
        __syncthreads();   // u/p writes visible before next row's spec reads
    }

    // outputs (float32): col4row[b][r-1] = j ; total_cost[b]
    // IEEE sqrtf here (cost threshold is loose; col4row must be exact).
    float tot = 0.f;
    #pragma unroll
    for (int k = 0; k < NPT; ++k) {
        int j = 4 * lane + k;
        int r = pl[k];                        // 1-based matched row
        out[b * NN + (r - 1)] = (float)j;
        float4 p4 = *(const float4*)&s_pred[r - 1][0];
        float dx = p4.x - gx[k], dy = p4.y - gy[k];
        float dz = p4.z - gz[k], dw = p4.w - gw[k];
        tot += sqrtf(dx * dx + dy * dy + dz * dz + dw * dw);
    }
    for (int off = 32; off; off >>= 1) tot += __shfl_xor(tot, off);
    if (lane == 0) out[NB * NN + b] = tot;
}

extern "C" void kernel_launch(void* const* d_in, const int* in_sizes, int n_in,
                              void* d_out, int out_size, void* d_ws, size_t ws_size,
                              hipStream_t stream) {
    const float* pred = (const float*)d_in[0];
    const float* gt   = (const float*)d_in[1];
    float* out = (float*)d_out;
    hipLaunchKernelGGL(hungarian_kernel, dim3(NB), dim3(64), 0, stream,
                       pred, gt, out);
}

// Round 11
// 2129.750 us; speedup vs baseline: 1.1842x; 1.0040x over previous
//
#include <hip/hip_runtime.h>
#include <math.h>

// Batched exact Hungarian (Jonker-Volgenant). One wave per batch; lane l owns
// contiguous columns j = 4l..4l+3 (jj = 4l+k+1): lowest-jj tie-break ==
// prefer-left local tree then lowest-lane ballot == jnp.argmin first-occur.
//
// Round-11: LDS-FREE Dijkstra iteration. r10 post-mortem: ~2k iters/batch,
// stall-bound (VALU issue ~13% of busy-CU cycles); the only per-iteration
// memory ops were the 2 speculative scattered ds_reads (u_spec b32 +
// pred b128, ~120cy, partially exposed; also the 1.64M bank-conflict
// source). Replace them with REGISTER MIRRORS maintained once per row:
//   ur[k]            = u[pl[k]]   (row-start value)
//   prx/pry/prz/prw[k] = pred[pl[k]]
// The local tree argmin carries 5 extra payloads (off-chain cndmasks that
// issue inside the DPP-ladder stall window); winner's ui/pr pulled by the
// same 5 readlanes. Maintenance: used-not-on-path columns take the same
// reconstructed value as the s_u writeback; augment-path columns read
// s_u[val]/s_pred[val] (wave-uniform broadcast; same-wave LDS ordering
// guarantees they see the writebacks). Epilogue uses mirrored pred.
// Everything else = r10 (branchless mark, deferred u/v, fma+fast-sqrt scan,
// min3 DPP reduce, ballot+ffs owner).
//
// Output dtype: harness reads d_out as float32; col4row stored as floats.

#define NB   32
#define NN   256
#define ND   4
#define NPT  4
#define INFV 1e9f

#if __has_builtin(__builtin_amdgcn_sqrtf)
__device__ __forceinline__ float fast_sqrtf(float x) { return __builtin_amdgcn_sqrtf(x); }
#else
__device__ __forceinline__ float fast_sqrtf(float x) {
    float r; asm volatile("v_sqrt_f32 %0, %1" : "=v"(r) : "v"(x)); return r;
}
#endif

__device__ __forceinline__ float wave_min_bcast(float x) {
    // 64-lane min in 5 dependent steps (min3 ladder); fill=1e9 never wins.
    const int fill = __float_as_int(INFV);
    int a, c;
    a = __builtin_amdgcn_update_dpp(fill, __float_as_int(x), 0x111, 0xF, 0xF, false); // row_shr:1
    c = __builtin_amdgcn_update_dpp(fill, __float_as_int(x), 0x112, 0xF, 0xF, false); // row_shr:2
    x = fminf(x, fminf(__int_as_float(a), __int_as_float(c)));      // cover 3
    a = __builtin_amdgcn_update_dpp(fill, __float_as_int(x), 0x113, 0xF, 0xF, false); // row_shr:3
    c = __builtin_amdgcn_update_dpp(fill, __float_as_int(x), 0x116, 0xF, 0xF, false); // row_shr:6
    x = fminf(x, fminf(__int_as_float(a), __int_as_float(c)));      // cover 9
    a = __builtin_amdgcn_update_dpp(fill, __float_as_int(x), 0x117, 0xF, 0xF, false); // row_shr:7
    x = fminf(x, __int_as_float(a));                                // cover 16
    a = __builtin_amdgcn_update_dpp(fill, __float_as_int(x), 0x142, 0xF, 0xF, false); // row_bcast:15
    x = fminf(x, __int_as_float(a));
    a = __builtin_amdgcn_update_dpp(fill, __float_as_int(x), 0x143, 0xF, 0xF, false); // row_bcast:31
    x = fminf(x, __int_as_float(a));                                // lane63 = global
    return __int_as_float(__builtin_amdgcn_readlane(__float_as_int(x), 63));
}

__device__ __forceinline__ float readlane_f(float v, int lane) {
    return __int_as_float(__builtin_amdgcn_readlane(__float_as_int(v), lane));
}

__global__ __launch_bounds__(64) void hungarian_kernel(
    const float* __restrict__ pred, const float* __restrict__ gt,
    float* __restrict__ out)
{
#pragma clang fp contract(off)
    const int b    = blockIdx.x;
    const int lane = threadIdx.x;

    __shared__ float s_pred[NN][ND];   // pred points, 16B rows (read-only after init)
    __shared__ float s_u[NN + 1];      // row potentials (1-based), row-start values
    __shared__ int   s_p[NN + 1];      // p[jj] = matched row (1-based)
    __shared__ int   s_way[NN];        // way, swizzled: [k*64 + lane]

    const float* pb = pred + (size_t)b * NN * ND;
    const float* gb = gt   + (size_t)b * NN * ND;

    #pragma unroll
    for (int k = 0; k < NPT; ++k) {
        int idx = lane + 64 * k;
        float4 pv = ((const float4*)pb)[idx];
        *(float4*)&s_pred[idx][0] = pv;
    }
    float gx[NPT], gy[NPT], gz[NPT], gw[NPT];
    #pragma unroll
    for (int k = 0; k < NPT; ++k) {
        float4 gv = ((const float4*)gb)[4 * lane + k];
        gx[k] = gv.x; gy[k] = gv.y; gz[k] = gv.z; gw[k] = gv.w;
    }
    #pragma unroll
    for (int k = 0; k < NPT; ++k) {
        int jj = lane + 64 * k;
        s_u[jj] = 0.f; s_p[jj] = 0;
    }
    if (lane == 0) { s_u[NN] = 0.f; s_p[NN] = 0; }
    // column potentials + register mirrors of the matched row's u and pred
    float v[NPT], ur[NPT], prx[NPT], pry[NPT], prz[NPT], prw[NPT];
    int pl[NPT];
    #pragma unroll
    for (int k = 0; k < NPT; ++k) {
        v[k] = 0.f; pl[k] = 0; ur[k] = 0.f;
        prx[k] = 0.f; pry[k] = 0.f; prz[k] = 0.f; prw[k] = 0.f;
    }
    const float FINF = __int_as_float(0x7f800000);   // +inf
    const float NINF = __int_as_float(0xff800000);   // -inf
    __syncthreads();

    for (int i = 1; i <= NN; ++i) {
        if (lane == 0) s_p[0] = i;
        int codes[NPT];                    // (jj | pl<<12), constant per row
        #pragma unroll
        for (int k = 0; k < NPT; ++k) codes[k] = (4 * lane + k + 1) | (pl[k] << 12);
        float minv[NPT], vm[NPT], ucol[NPT], mcol[NPT];
        int   wayr[NPT];
        #pragma unroll
        for (int k = 0; k < NPT; ++k) {
            minv[k] = INFV; vm[k] = v[k]; ucol[k] = 0.f; mcol[k] = 0.f; wayr[k] = 0;
        }
        float u_i = 0.f;                          // running sum of deltas == ref u[i]
        int   j1  = 0;
        float ui  = 0.f;                          // u[p[j1]] row-start value
        float4 pr = *(const float4*)&s_pred[i - 1][0];
        int   i0n = i;

        for (int it = 0; it < NN + 2; ++it) {
            // branchless mark: jm1=-1 on first iter matches no lane
            const int   jm1 = j1 - 1;             // wave-uniform
            const float bu  = ui - u_i;
            #pragma unroll
            for (int k = 0; k < NPT; ++k) {
                bool hit = (4 * lane + k) == jm1;
                vm[k]   = hit ? NINF : vm[k];     // freezes wayr; cur=+inf
                minv[k] = hit ? FINF : minv[k];   // masks argmin
                ucol[k] = hit ? bu   : ucol[k];   // u_new = ucol + u_i_end
                mcol[k] = hit ? u_i  : mcol[k];   // v_new = (v - u_i_end) + mcol
            }
            // scan owned columns; fma ss + fast sqrt (decisions only)
            #pragma unroll
            for (int k = 0; k < NPT; ++k) {
                float dx = pr.x - gx[k], dy = pr.y - gy[k];
                float dz = pr.z - gz[k], dw = pr.w - gw[k];
                float ss = dx * dx;
                ss = __builtin_fmaf(dy, dy, ss);
                ss = __builtin_fmaf(dz, dz, ss);
                ss = __builtin_fmaf(dw, dw, ss);
                float cur = (fast_sqrtf(ss) - ui) - vm[k];   // used: +inf
                bool upd = cur < minv[k];
                wayr[k] = upd ? j1 : wayr[k];
                minv[k] = fminf(minv[k], cur);
            }
            // 2-level tree argmin on minv with payloads (code + mirrored
            // u/pred of the candidate's matched row; strict <, prefer-left)
            bool s01 = minv[1] < minv[0];
            float v01 = s01 ? minv[1] : minv[0];
            int   c01 = s01 ? codes[1] : codes[0];
            float u01 = s01 ? ur[1] : ur[0];
            float x01 = s01 ? prx[1] : prx[0];
            float y01 = s01 ? pry[1] : pry[0];
            float z01 = s01 ? prz[1] : prz[0];
            float w01 = s01 ? prw[1] : prw[0];
            bool s23 = minv[3] < minv[2];
            float v23 = s23 ? minv[3] : minv[2];
            int   c23 = s23 ? codes[3] : codes[2];
            float u23 = s23 ? ur[3] : ur[2];
            float x23 = s23 ? prx[3] : prx[2];
            float y23 = s23 ? pry[3] : pry[2];
            float z23 = s23 ? prz[3] : prz[2];
            float w23 = s23 ? prw[3] : prw[2];
            bool sF  = v23 < v01;
            float best       = sF ? v23 : v01;
            int   code_local = sF ? c23 : c01;
            float usel = sF ? u23 : u01;
            float xsel = sF ? x23 : x01;
            float ysel = sF ? y23 : y01;
            float zsel = sF ? z23 : z01;
            float wsel = sF ? w23 : w01;
            // wave argmin: value min via DPP; owner = lowest lane at min
            const float gmin = wave_min_bcast(best);
            unsigned long long msk = __ballot(best == gmin);
            int owner = __ffsll(msk) - 1;
            int code  = __builtin_amdgcn_readlane(code_local, owner);
            int j1n   = code & 0xFFF;
            i0n       = code >> 12;
            // minimal updates: minv -= delta (used stay +inf); u_i += delta
            const float delta = gmin;
            #pragma unroll
            for (int k = 0; k < NPT; ++k) minv[k] -= delta;
            u_i += delta;
            j1 = j1n;
            if (i0n == 0) break;                  // free column (updates done)
            // pull winner's mirrored values (no LDS!)
            ui   = readlane_f(usel, owner);
            pr.x = readlane_f(xsel, owner);
            pr.y = readlane_f(ysel, owner);
            pr.z = readlane_f(zsel, owner);
            pr.w = readlane_f(wsel, owner);
        }

        // flush way registers to LDS (stride-1 per k, conflict-free)
        #pragma unroll
        for (int k = 0; k < NPT; ++k) s_way[(k << 6) + lane] = wayr[k];
        __syncthreads();   // way/p0 writes visible before augment reads
        // deferred write-back (used == minv pinned to +inf); also refresh
        // the register mirror ur[k] with the same reconstructed value
        #pragma unroll
        for (int k = 0; k < NPT; ++k) {
            bool used = (minv[k] == FINF);
            float un = ucol[k] + u_i;
            if (used) s_u[pl[k]] = un;                   // exec-masked ds_write
            ur[k] = used ? un : ur[k];
            v[k]  = used ? ((v[k] - u_i) + mcol[k]) : v[k];
        }
        if (lane == 0) s_u[i] = u_i;
        // augment along way chain; maintain pl + mirrors for path columns
        int j = j1;
        while (j != 0) {
            int jm1 = j - 1;
            int jp  = s_way[((jm1 & 3) << 6) + (jm1 >> 2)];
            int val = s_p[jp];                            // row moving into col j
            if (lane == 0) s_p[j] = val;
            float  unew = s_u[val];                       // broadcast (post-writeback)
            float4 pnew = *(const float4*)&s_pred[val - 1][0];
            bool own = (jm1 >> 2) == lane;
            int  kk  = jm1 & 3;
            #pragma unroll
            for (int k = 0; k < NPT; ++k) {
                bool hit = own && (kk == k);
                pl[k]  = hit ? val    : pl[k];
                ur[k]  = hit ? unew   : ur[k];
                prx[k] = hit ? pnew.x : prx[k];
                pry[k] = hit ? pnew.y : pry[k];
                prz[k] = hit ? pnew.z : prz[k];
                prw[k] = hit ? pnew.w : prw[k];
            }
            j = jp;
        }
        __syncthreads();   // augment writes visible before next row
    }

    // outputs (float32): col4row[b][r-1] = j ; total_cost[b]
    // IEEE sqrtf here (cost threshold is loose; col4row must be exact).
    float tot = 0.f;
    #pragma unroll
    for (int k = 0; k < NPT; ++k) {
        int j = 4 * lane + k;
        int r = pl[k];                        // 1-based matched row
        out[b * NN + (r - 1)] = (float)j;
        float dx = prx[k] - gx[k], dy = pry[k] - gy[k];
        float dz = prz[k] - gz[k], dw = prw[k] - gw[k];
        tot += sqrtf(dx * dx + dy * dy + dz * dz + dw * dw);
    }
    for (int off = 32; off; off >>= 1) tot += __shfl_xor(tot, off);
    if (lane == 0) out[NB * NN + b] = tot;
}

extern "C" void kernel_launch(void* const* d_in, const int* in_sizes, int n_in,
                              void* d_out, int out_size, void* d_ws, size_t ws_size,
                              hipStream_t stream) {
    const float* pred = (const float*)d_in[0];
    const float* gt   = (const float*)d_in[1];
    float* out = (float*)d_out;
    hipLaunchKernelGGL(hungarian_kernel, dim3(NB), dim3(64), 0, stream,
                       pred, gt, out);
}